// Round 8
// baseline (383.701 us; speedup 1.0000x reference)
//
#include <hip/hip_runtime.h>
#include <math.h>

// Problem constants (reference setup_inputs): N=8192, K=32, D=128, fp32.
constexpr int NN = 8192;
constexpr int K  = 32;
constexpr int D  = 128;
constexpr int HS  = 136;   // bf16 plane row stride (elems): 272 B (16B-mult, bank-rotating)
constexpr int HDS = 132;   // hd_s f32 row stride (bank-rotating)
constexpr float ALPHA = 0.2f;
constexpr float MASKV = -9e15f;
constexpr float EPS   = 1e-8f;

typedef __bf16 bf16x8 __attribute__((ext_vector_type(8)));
typedef __bf16 bf16x4 __attribute__((ext_vector_type(4)));
typedef float  f32x4  __attribute__((ext_vector_type(4)));

__device__ __forceinline__ float dot4v(const f32x4 a, const f32x4 b) {
    return fmaf(a[0], b[0], fmaf(a[1], b[1], fmaf(a[2], b[2], a[3] * b[3])));
}

// ---------------------------------------------------------------------------
// Pre-kernel: build MFMA-fragment-ordered bf16 hi/lo tables for BOTH W halves.
// tabs = [bot_hi | bot_lo | top_hi | top_lo], 16384 elems each.
// Fragment (s,nt): lane l, elem j = W[rowbase + 32s + 8*(l>>4) + j][16nt + (l&15)].
// ---------------------------------------------------------------------------
__global__ __launch_bounds__(256) void conv_w(const float* __restrict__ W,
                                              __bf16* __restrict__ tabs) {
    const int idx = blockIdx.x * 256 + threadIdx.x;      // 32768 total
    const int j = idx & 7, l = (idx >> 3) & 63, nt = (idx >> 9) & 7;
    const int s = (idx >> 12) & 3, half = idx >> 14;     // 0 = bot(W[D:2D]), 1 = top(W[0:D])
    const int e = 32 * s + 8 * (l >> 4) + j;
    const int c = 16 * nt + (l & 15);
    const float x = W[(size_t)((half ? 0 : D) + e) * D + c];
    const __bf16 h = (__bf16)x;
    const int fi = idx & 16383;
    tabs[half * 32768 + fi]         = h;
    tabs[half * 32768 + 16384 + fi] = (__bf16)(x - (float)h);
}

// ---------------------------------------------------------------------------
// Fused 2-layer GAT-relation, one 512-thread block per n, 4 blocks/CU.
// A:  stage dst (bf16 hi/lo planes), src, b, adj; rel -> registers.
// C:  split-bf16 MFMA (setprio-wrapped): hd = dst@W_bot(+b) -> LDS;
//     dstWt = dst@W_top -> regs (acc2/acc3).  Then sW1 GEMV -> sWp
//     (placed here so its L2 latency hides under other waves' MFMA).
// D:  layer-1 cosine scalars; cache A,B,R.
// G': softmax1 REPLICATED per wave (no barrier) + sW2 = att1·dstWt + sW1.
// I:  layer-2 scalars.  J: softmax2.  K: out = (att1+att2)·dst + src.
// 6 barriers (was 7).
// ---------------------------------------------------------------------------
__global__ __launch_bounds__(512, 8) void gat_fused(
    const float* __restrict__ src,
    const float* __restrict__ dst,
    const float* __restrict__ rel,
    const float* __restrict__ W,
    const float* __restrict__ b,
    const int*   __restrict__ adj,
    const __bf16* __restrict__ tabs,
    float* __restrict__ out)
{
    __shared__ __align__(16) __bf16 hi_s[K * HS];   // 8704 B
    __shared__ __align__(16) __bf16 lo_s[K * HS];   // 8704 B
    __shared__ __align__(16) float  hd_s[K * HDS];  // 16896 B
    __shared__ __align__(16) float  x_s[D];         // src
    __shared__ __align__(16) float  sWp[4 * D];     // sW1 e-split partials
    __shared__ __align__(16) float  sW_s[D];        // sW2
    __shared__ __align__(16) float  b_s[D];
    __shared__ float e_s[K], att1_s[K], ats_s[K], A_s[K], B_s[K], R_s[K];
    __shared__ int   adj_s[K];

    const int n  = blockIdx.x;
    const int t  = threadIdx.x;
    const int w  = t >> 6;        // wave 0..7
    const int l  = t & 63;
    const int lr = l & 15;        // MFMA tile row/col
    const int lk = l >> 4;        // MFMA k-quad
    const int kc = 4 * w + (l & 3);  // dot-phase k (16 lanes per k)
    const int q2 = l >> 2;           // dot-phase elem-quad 0..15

    const float* dstn = dst + (size_t)n * K * D;
    const float* reln = rel + (size_t)n * K * D;
    const __bf16* wbh = tabs;
    const __bf16* wbl = tabs + 16384;
    const __bf16* wth = tabs + 32768;
    const __bf16* wtl = tabs + 49152;

    // ==== phase A: stage (pure staging; no GEMV here) ====
    if (t < 32)       ((float4*)x_s)[t]      = ((const float4*)(src + (size_t)n * D))[t];
    else if (t < 64)  ((float4*)b_s)[t - 32] = ((const float4*)b)[t - 32];
    else if (t < 96)  adj_s[t - 64] = adj[n * K + (t - 64)];

    // rel for this thread's (kc, q2) — held in registers through D and I.
    const f32x4 rv0 = *(const f32x4*)(reln + kc * D + 4 * q2);
    const f32x4 rv1 = *(const f32x4*)(reln + kc * D + 4 * (q2 + 16));

    #pragma unroll
    for (int jj = 0; jj < 2; ++jj) {
        const int idx = t + 512 * jj;          // [0, K*D/4)
        const int row = idx >> 5, c4 = idx & 31;
        const float4 g = ((const float4*)dstn)[idx];
        const float gv[4] = {g.x, g.y, g.z, g.w};
        bf16x4 hv, lv;
        #pragma unroll
        for (int c = 0; c < 4; ++c) {
            const __bf16 h = (__bf16)gv[c];
            hv[c] = h;
            lv[c] = (__bf16)(gv[c] - (float)h);
        }
        *(bf16x4*)(hi_s + row * HS + 4 * c4) = hv;
        *(bf16x4*)(lo_s + row * HS + 4 * c4) = lv;
    }
    __syncthreads();   // B1

    // ==== phase C: MFMA — hd (bot) to LDS, dstWt (top) to regs; then sW1 GEMV ====
    f32x4 acc2 = {0,0,0,0}, acc3 = {0,0,0,0};       // dstWt k 0-15 / 16-31
    {
        f32x4 acc0 = {0,0,0,0}, acc1 = {0,0,0,0};   // hd k 0-15 / 16-31
        __builtin_amdgcn_s_setprio(1);
        #pragma unroll
        for (int ks = 0; ks < 4; ++ks) {
            const int off = lr * HS + 32 * ks + 8 * lk;
            const bf16x8 ah0 = *(const bf16x8*)(hi_s + off);
            const bf16x8 al0 = *(const bf16x8*)(lo_s + off);
            const bf16x8 ah1 = *(const bf16x8*)(hi_s + off + 16 * HS);
            const bf16x8 al1 = *(const bf16x8*)(lo_s + off + 16 * HS);
            const size_t fo = (size_t)((ks * 8 + w) * 64 + l) * 8;
            {
                const bf16x8 bh = *(const bf16x8*)(wbh + fo);
                const bf16x8 bl = *(const bf16x8*)(wbl + fo);
                acc0 = __builtin_amdgcn_mfma_f32_16x16x32_bf16(ah0, bh, acc0, 0, 0, 0);
                acc0 = __builtin_amdgcn_mfma_f32_16x16x32_bf16(ah0, bl, acc0, 0, 0, 0);
                acc0 = __builtin_amdgcn_mfma_f32_16x16x32_bf16(al0, bh, acc0, 0, 0, 0);
                acc1 = __builtin_amdgcn_mfma_f32_16x16x32_bf16(ah1, bh, acc1, 0, 0, 0);
                acc1 = __builtin_amdgcn_mfma_f32_16x16x32_bf16(ah1, bl, acc1, 0, 0, 0);
                acc1 = __builtin_amdgcn_mfma_f32_16x16x32_bf16(al1, bh, acc1, 0, 0, 0);
            }
            {
                const bf16x8 th = *(const bf16x8*)(wth + fo);
                const bf16x8 tl = *(const bf16x8*)(wtl + fo);
                acc2 = __builtin_amdgcn_mfma_f32_16x16x32_bf16(ah0, th, acc2, 0, 0, 0);
                acc2 = __builtin_amdgcn_mfma_f32_16x16x32_bf16(ah0, tl, acc2, 0, 0, 0);
                acc2 = __builtin_amdgcn_mfma_f32_16x16x32_bf16(al0, th, acc2, 0, 0, 0);
                acc3 = __builtin_amdgcn_mfma_f32_16x16x32_bf16(ah1, th, acc3, 0, 0, 0);
                acc3 = __builtin_amdgcn_mfma_f32_16x16x32_bf16(ah1, tl, acc3, 0, 0, 0);
                acc3 = __builtin_amdgcn_mfma_f32_16x16x32_bf16(al1, th, acc3, 0, 0, 0);  // FIXED: was (al1,tl)
            }
        }
        __builtin_amdgcn_s_setprio(0);
        // C/D layout (m89): col = lane&15, row = (lane>>4)*4 + reg
        const float bc = b_s[16 * w + lr];
        #pragma unroll
        for (int r = 0; r < 4; ++r) {
            hd_s[(4 * lk + r) * HDS + 16 * w + lr]      = acc0[r] + bc;
            hd_s[(16 + 4 * lk + r) * HDS + 16 * w + lr] = acc1[r] + bc;
        }
    }
    {   // sW1 GEMV partials: e-quarter es, output col dd; L2 latency hides
        // under other waves' MFMA work (post-B1 region).
        const int dd = t & 127, es = t >> 7;
        const float* sp = x_s + 32 * es;
        const float* Wp = W + (size_t)(32 * es) * D + dd;
        float acc = 0.f;
        #pragma unroll 8
        for (int e = 0; e < 32; ++e)
            acc = fmaf(sp[e], Wp[(size_t)e * D], acc);
        sWp[es * D + dd] = acc;
    }
    __syncthreads();   // B2

    // ==== phase D: layer-1 scalars + e1; cache A,B,R ====
    {
        float a_ = 0.f, bb = 0.f, r2 = 0.f, sr = 0.f, sh = 0.f, ss = 0.f;
        #pragma unroll
        for (int it = 0; it < 2; ++it) {
            const int f = q2 + 16 * it;
            const f32x4 rv = it ? rv1 : rv0;
            const f32x4 hv = *(const f32x4*)(hd_s + kc * HDS + 4 * f);
            f32x4 sv = ((const f32x4*)sWp)[f];
            sv += ((const f32x4*)sWp)[32 + f];
            sv += ((const f32x4*)sWp)[64 + f];
            sv += ((const f32x4*)sWp)[96 + f];
            a_ += dot4v(hv, rv);  bb += dot4v(hv, hv);  r2 += dot4v(rv, rv);
            sr += dot4v(sv, rv);  sh += dot4v(sv, hv);  ss += dot4v(sv, sv);
        }
        #pragma unroll
        for (int m = 4; m < 64; m <<= 1) {
            a_ += __shfl_xor(a_, m);  bb += __shfl_xor(bb, m);
            r2 += __shfl_xor(r2, m);  sr += __shfl_xor(sr, m);
            sh += __shfl_xor(sh, m);  ss += __shfl_xor(ss, m);
        }
        if (q2 == 0) {
            const float R   = fmaxf(sqrtf(r2), EPS);
            const float hh  = ss + 2.f * sh + bb;          // ||h1||^2
            const float den = fmaxf(sqrtf(hh), EPS) * R;
            float e = (sr + a_) / den;
            e = e > 0.f ? e : ALPHA * e;                   // LeakyReLU
            if (adj_s[kc] <= 0) e = MASKV;                 // mask
            e_s[kc] = e;  A_s[kc] = a_;  B_s[kc] = bb;  R_s[kc] = R;
        }
    }
    __syncthreads();   // B3

    // ==== phase G' (+softmax1, replicated per wave — no barrier between) ====
    {
        const float v = e_s[l & 31];                       // broadcast read
        float m = v;
        #pragma unroll
        for (int s = 16; s > 0; s >>= 1) m = fmaxf(m, __shfl_xor(m, s));
        const float p = expf(v - m);
        float sm = p;
        #pragma unroll
        for (int s = 16; s > 0; s >>= 1) sm += __shfl_xor(sm, s);
        const float att1v = p / sm;                        // att1 for k = l&31
        if (t < 32) att1_s[t] = att1v;                     // wave 0 publishes for J

        float s2 = 0.f;
        #pragma unroll
        for (int r = 0; r < 4; ++r) {
            s2 = fmaf(__shfl(att1v, 4 * lk + r),      acc2[r], s2);
            s2 = fmaf(__shfl(att1v, 16 + 4 * lk + r), acc3[r], s2);
        }
        s2 += __shfl_xor(s2, 16);
        s2 += __shfl_xor(s2, 32);
        if (lk == 0) {
            const int col = 16 * w + lr;
            sW_s[col] = s2 + ((sWp[col] + sWp[128 + col]) +
                              (sWp[256 + col] + sWp[384 + col]));
        }
    }
    __syncthreads();   // B5

    // ==== phase I: layer-2 scalars + e2 (rel regs, hd LDS, A/B/R cached) ====
    {
        float sr = 0.f, sh = 0.f, ss = 0.f;
        #pragma unroll
        for (int it = 0; it < 2; ++it) {
            const int f = q2 + 16 * it;
            const f32x4 rv = it ? rv1 : rv0;
            const f32x4 hv = *(const f32x4*)(hd_s + kc * HDS + 4 * f);
            const f32x4 sv = ((const f32x4*)sW_s)[f];
            sr += dot4v(sv, rv);  sh += dot4v(sv, hv);  ss += dot4v(sv, sv);
        }
        #pragma unroll
        for (int m = 4; m < 64; m <<= 1) {
            sr += __shfl_xor(sr, m);  sh += __shfl_xor(sh, m);  ss += __shfl_xor(ss, m);
        }
        if (q2 == 0) {
            const float hh  = ss + 2.f * sh + B_s[kc];     // ||h2||^2
            const float den = fmaxf(sqrtf(hh), EPS) * R_s[kc];
            float e = (sr + A_s[kc]) / den;
            e = e > 0.f ? e : ALPHA * e;
            if (adj_s[kc] <= 0) e = MASKV;
            e_s[kc] = e;
        }
    }
    __syncthreads();   // B6

    // ==== phase J: softmax2 -> attsum = att1 + att2 ====
    if (t < K) {
        float v = e_s[t], m = v;
        #pragma unroll
        for (int s = 16; s > 0; s >>= 1) m = fmaxf(m, __shfl_xor(m, s));
        const float p = expf(v - m);
        float sm = p;
        #pragma unroll
        for (int s = 16; s > 0; s >>= 1) sm += __shfl_xor(sm, s);
        ats_s[t] = att1_s[t] + p / sm;
    }
    __syncthreads();   // B7

    // ==== phase K: out = Sum_k attsum_k * dst_k + src ====
    if (t < D) {
        float agg = 0.f;
        #pragma unroll
        for (int k = 0; k < K; ++k) {
            const float f = (float)hi_s[k * HS + t] + (float)lo_s[k * HS + t];
            agg = fmaf(ats_s[k], f, agg);
        }
        out[(size_t)n * D + t] = agg + x_s[t];
    }
}

extern "C" void kernel_launch(void* const* d_in, const int* in_sizes, int n_in,
                              void* d_out, int out_size, void* d_ws, size_t ws_size,
                              hipStream_t stream) {
    const float* src = (const float*)d_in[0];
    const float* dst = (const float*)d_in[1];
    const float* rel = (const float*)d_in[2];
    const float* W   = (const float*)d_in[3];
    const float* b   = (const float*)d_in[4];
    const int*   adj = (const int*)d_in[5];
    float* out = (float*)d_out;

    __bf16* tabs = (__bf16*)d_ws;   // 4 x 16384 bf16 = 128 KB

    conv_w<<<128, 256, 0, stream>>>(W, tabs);
    gat_fused<<<NN, 512, 0, stream>>>(src, dst, rel, W, b, adj, tabs, out);
}